// Round 7
// baseline (3308.720 us; speedup 1.0000x reference)
//
#include <hip/hip_runtime.h>
#include <hip/hip_bf16.h>
#include <math.h>

#define NP 1024
#define NL 18
#define LOG2048 7.6246189861593985f
#define LOG1024 6.9314718055994531f
#define ZLD 1028           // row stride of Z matrices (floats, 16B-aligned rows)
#define ZBS (1025 * ZLD)   // batch stride
#define UVS 1040           // u/v per-batch stride

typedef __attribute__((ext_vector_type(8))) short short8;
typedef __attribute__((ext_vector_type(4))) float f32x4;
typedef unsigned short u16;

__device__ __forceinline__ u16 f2b(float f) {
    __hip_bfloat16 h = __float2bfloat16(f);
    return *reinterpret_cast<u16*>(&h);
}
__device__ __forceinline__ float b2f(u16 u) {
    __hip_bfloat16 h;
    *reinterpret_cast<u16*>(&h) = u;
    return __bfloat162float(h);
}
__device__ __forceinline__ short8 ld8(const u16* p) { return *reinterpret_cast<const short8*>(p); }

// ---------------- block reduction (blockDim = 256) ----------------
__device__ __forceinline__ float block_reduce_sum(float v, float* red) {
    int tid = threadIdx.x;
    red[tid] = v; __syncthreads();
    for (int s = 128; s > 0; s >>= 1) {
        if (tid < s) red[tid] += red[tid + s];
        __syncthreads();
    }
    float r = red[0]; __syncthreads();
    return r;
}

// ---------------- weight cast / permute ----------------
__global__ void castperm_kernel(const float* __restrict__ src, u16* __restrict__ dst,
                                int R, int C, int mode)
{
    size_t idx = (size_t)blockIdx.x * 256 + threadIdx.x;
    int rc = R * C;
    size_t mat = idx / rc; int rem = (int)(idx % rc);
    int r = rem / C, c = rem % C;
    if (mode == 1) r = ((r & 63) << 2) | (r >> 6);
    dst[idx] = f2b(src[mat * rc + (size_t)r * C + c]);
}

// WmT[l][p][i] = merge_w[l][i][perm(p)]
__global__ void castmergeT_kernel(const float* __restrict__ src, u16* __restrict__ dst)
{
    size_t idx = (size_t)blockIdx.x * 256 + threadIdx.x; // 18*65536
    int l = (int)(idx >> 16);
    int rem = (int)(idx & 65535);
    int p = rem >> 8, i = rem & 255;
    int cp = ((p & 63) << 2) | (p >> 6);
    dst[idx] = f2b(src[(size_t)l * 65536 + (size_t)i * 256 + cp]);
}

__global__ void castsliceA_kernel(const float* __restrict__ src, u16* __restrict__ dst)
{
    size_t idx = (size_t)blockIdx.x * 256 + threadIdx.x; // 18*512*256
    int l = (int)(idx / (512 * 256));
    int rem = (int)(idx % (512 * 256));
    int o = rem >> 8, c = rem & 255;
    dst[(size_t)l * 262144 + (size_t)o * 512 + c] = f2b(src[(size_t)l * 262144 + (size_t)o * 512 + c]);
}

__global__ void castsliceB_kernel(const float* __restrict__ src, u16* __restrict__ dst)
{
    size_t idx = (size_t)blockIdx.x * 256 + threadIdx.x; // 18*512*256
    int l = (int)(idx / (512 * 256));
    int rem = (int)(idx % (512 * 256));
    int o = rem >> 8, i = rem & 255;
    dst[idx] = f2b(src[(size_t)l * 262144 + (size_t)o * 512 + 256 + i]);
}

// Wm1f[l][o][256+p] = sum_i Wtmp[l][o][i] * WmT[l][p][i]
__global__ __launch_bounds__(256) void wfuse_mfma(
    const u16* __restrict__ Wtmp, const u16* __restrict__ WmT, u16* __restrict__ Wm1f)
{
    const int l = blockIdx.z;
    const u16* A = Wtmp + (size_t)l * 131072;
    const u16* B = WmT + (size_t)l * 65536;
    u16* out = Wm1f + (size_t)l * 262144;
    const int tid = threadIdx.x;
    const int wv = tid >> 6, lane = tid & 63, l15 = lane & 15, q = lane >> 4;
    const int r0 = blockIdx.x * 64, o0 = blockIdx.y * 64;
    const int wo = (wv & 1) * 32, wn = (wv >> 1) * 32;
    f32x4 acc[2][2] = {};
    const int oa0 = o0 + wo + l15, oa1 = oa0 + 16;
    const int rb0 = r0 + wn + l15, rb1 = rb0 + 16;
    for (int k0 = 0; k0 < 256; k0 += 32) {
        const int k = k0 + q * 8;
        short8 a0 = ld8(A + (size_t)oa0 * 256 + k);
        short8 a1 = ld8(A + (size_t)oa1 * 256 + k);
        short8 b0 = ld8(B + (size_t)rb0 * 256 + k);
        short8 b1 = ld8(B + (size_t)rb1 * 256 + k);
        acc[0][0] = __builtin_amdgcn_mfma_f32_16x16x32_bf16(a0, b0, acc[0][0], 0, 0, 0);
        acc[0][1] = __builtin_amdgcn_mfma_f32_16x16x32_bf16(a0, b1, acc[0][1], 0, 0, 0);
        acc[1][0] = __builtin_amdgcn_mfma_f32_16x16x32_bf16(a1, b0, acc[1][0], 0, 0, 0);
        acc[1][1] = __builtin_amdgcn_mfma_f32_16x16x32_bf16(a1, b1, acc[1][1], 0, 0, 0);
    }
    #pragma unroll
    for (int i = 0; i < 2; i++)
        #pragma unroll
        for (int j = 0; j < 2; j++)
            #pragma unroll
            for (int rg = 0; rg < 4; rg++)
                out[(size_t)(o0 + wo + i * 16 + q * 4 + rg) * 512 + 256 + r0 + wn + j * 16 + l15]
                    = f2b(acc[i][j][rg]);
}

// b1p[l][o] = mlp1_b[l][o] + sum_i mlp1_w[l][o][256+i]*merge_b[l][i]
__global__ void mlp1bias_kernel(const float* __restrict__ w1, const float* __restrict__ b1,
                                const float* __restrict__ bm, float* __restrict__ b1p)
{
    int idx = blockIdx.x * 256 + threadIdx.x; // 18*512
    int l = idx >> 9, o = idx & 511;
    float s = b1[idx];
    const float* wrow = w1 + (size_t)l * 262144 + (size_t)o * 512 + 256;
    const float* bmr = bm + l * 256;
    for (int i = 0; i < 256; i++) s = fmaf(wrow[i], bmr[i], s);
    b1p[idx] = s;
}

__global__ void permb_kernel(const float* __restrict__ src, float* __restrict__ dst)
{
    int idx = blockIdx.x * 256 + threadIdx.x; // 54*256
    int mat = idx >> 8, r = idx & 255;
    int o = ((r & 63) << 2) | (r >> 6);
    dst[idx] = src[mat * 256 + o];
}

// ---------------- desc -> X (transpose to [bt][n][256] f32) ----------------
__global__ void desc_t_kernel(const float* __restrict__ d0, const float* __restrict__ d1,
                              float* __restrict__ X)
{
    __shared__ float tile[32][33];
    const int bt = blockIdx.z, b = bt & 1;
    const float* d = (bt < 2) ? d0 : d1;
    const int c0 = blockIdx.x * 32, n0 = blockIdx.y * 32;
    for (int rr = threadIdx.y; rr < 32; rr += 8)
        tile[rr][threadIdx.x] = d[((size_t)b * 256 + c0 + rr) * NP + n0 + threadIdx.x];
    __syncthreads();
    for (int rr = threadIdx.y; rr < 32; rr += 8)
        X[((size_t)bt * NP + n0 + rr) * 256 + c0 + threadIdx.x] = tile[threadIdx.x][rr];
}

// ---------------- kenc first conv (3->32) ----------------
__global__ __launch_bounds__(256) void kenc1_kernel(
    const float* __restrict__ k0, const float* __restrict__ k1,
    const float* __restrict__ s0, const float* __restrict__ s1,
    const float* __restrict__ w, const float* __restrict__ bias, u16* __restrict__ A1)
{
    int t = blockIdx.x * 256 + threadIdx.x; // 4096*32
    int r = t >> 5, o = t & 31;
    int bt = r >> 10, n = r & 1023, b = bt & 1;
    const float* kp = (bt < 2) ? k0 : k1;
    const float* sc = (bt < 2) ? s0 : s1;
    float x0 = (kp[((size_t)b * NP + n) * 2 + 0] - 320.f) * (1.f / 448.f);
    float x1 = (kp[((size_t)b * NP + n) * 2 + 1] - 240.f) * (1.f / 448.f);
    float x2 = sc[(size_t)b * NP + n];
    float a = w[o * 3 + 0] * x0 + w[o * 3 + 1] * x1 + w[o * 3 + 2] * x2 + bias[o];
    A1[(size_t)r * 32 + o] = f2b(a);
}

// ---------------- BatchNorm (kenc path) ----------------
__global__ __launch_bounds__(256) void bn_small_kernel(const u16* __restrict__ Xc, int C,
    const float* __restrict__ g, const float* __restrict__ be, float2* __restrict__ s01)
{
    __shared__ float red[256];
    const int s = blockIdx.x / C, c = blockIdx.x % C;
    const int tid = threadIdx.x;
    float sum = 0.f, sq = 0.f;
    const u16* p = Xc + (size_t)s * 2048 * C + c;
    for (int j = tid; j < 2048; j += 256) { float v = b2f(p[(size_t)j * C]); sum += v; sq = fmaf(v, v, sq); }
    sum = block_reduce_sum(sum, red);
    sq  = block_reduce_sum(sq, red);
    if (tid == 0) {
        float mu = sum * (1.f / 2048.f);
        float var = fmaxf(sq * (1.f / 2048.f) - mu * mu, 0.f);
        float s1 = g[c] * rsqrtf(var + 1e-5f);
        s01[s * C + c] = make_float2(s1, be[c] - s1 * mu);
    }
}

__global__ __launch_bounds__(256) void bn_apply_kernel(u16* __restrict__ Xc,
    const float2* __restrict__ s01, int C)
{
    size_t idx = (size_t)blockIdx.x * 256 + threadIdx.x;
    int c = (int)(idx % C);
    int s = (int)(idx / ((size_t)2048 * C));
    float2 p = s01[s * C + c];
    float v = fmaf(p.x, b2f(Xc[idx]), p.y);
    Xc[idx] = f2b(fmaxf(v, 0.f));
}

// ---------------- generic MFMA conv GEMM ----------------
template<int K, int MODE>
__global__ __launch_bounds__(256) void gemm_mfma(
    const u16* __restrict__ W, const float* __restrict__ bias,
    const u16* __restrict__ B1, const u16* __restrict__ B2, int split,
    int srcXor, u16* __restrict__ outB, float* __restrict__ Xf, u16* __restrict__ Xb, int Cout)
{
    const int tid = threadIdx.x;
    const int wv = tid >> 6, lane = tid & 63, l15 = lane & 15, q = lane >> 4;
    const int r0 = blockIdx.x * 64, o0 = blockIdx.y * 64;
    const int wo = (wv & 1) * 32, wn = (wv >> 1) * 32;
    f32x4 acc[2][2] = {};
    const int oa0 = o0 + wo + l15, oa1 = oa0 + 16;
    const int rb0 = (r0 + wn + l15) ^ srcXor, rb1 = (r0 + wn + 16 + l15) ^ srcXor;
    for (int k0 = 0; k0 < K; k0 += 32) {
        const int k = k0 + q * 8;
        short8 a0 = ld8(W + (size_t)oa0 * K + k);
        short8 a1 = ld8(W + (size_t)oa1 * K + k);
        const u16* bp; int ld, kk;
        if (k0 < split) { bp = B1; ld = split; kk = k; }
        else            { bp = B2; ld = K - split; kk = k - split; }
        short8 b0 = ld8(bp + (size_t)rb0 * ld + kk);
        short8 b1 = ld8(bp + (size_t)rb1 * ld + kk);
        acc[0][0] = __builtin_amdgcn_mfma_f32_16x16x32_bf16(a0, b0, acc[0][0], 0, 0, 0);
        acc[0][1] = __builtin_amdgcn_mfma_f32_16x16x32_bf16(a0, b1, acc[0][1], 0, 0, 0);
        acc[1][0] = __builtin_amdgcn_mfma_f32_16x16x32_bf16(a1, b0, acc[1][0], 0, 0, 0);
        acc[1][1] = __builtin_amdgcn_mfma_f32_16x16x32_bf16(a1, b1, acc[1][1], 0, 0, 0);
    }
    #pragma unroll
    for (int i = 0; i < 2; i++) {
        const int ob = o0 + wo + i * 16 + q * 4;
        f32x4 bi = *reinterpret_cast<const f32x4*>(bias + ob);
        #pragma unroll
        for (int j = 0; j < 2; j++) {
            const int rr = r0 + wn + j * 16 + l15;
            if (MODE == 0) {
                ushort4 pk;
                pk.x = f2b(acc[i][j][0] + bi[0]);
                pk.y = f2b(acc[i][j][1] + bi[1]);
                pk.z = f2b(acc[i][j][2] + bi[2]);
                pk.w = f2b(acc[i][j][3] + bi[3]);
                *reinterpret_cast<ushort4*>(outB + (size_t)rr * Cout + ob) = pk;
            } else {
                float* xp = Xf + (size_t)rr * Cout + ob;
                f32x4 xo = *reinterpret_cast<f32x4*>(xp);
                #pragma unroll
                for (int r = 0; r < 4; r++) xo[r] += acc[i][j][r] + bi[r];
                *reinterpret_cast<f32x4*>(xp) = xo;
                ushort4 pk;
                pk.x = f2b(xo[0]); pk.y = f2b(xo[1]); pk.z = f2b(xo[2]); pk.w = f2b(xo[3]);
                *reinterpret_cast<ushort4*>(Xb + (size_t)rr * Cout + ob) = pk;
            }
        }
    }
}

// ---------------- fused QKV projection ----------------
__global__ __launch_bounds__(256) void qkv_mfma(
    const u16* __restrict__ Wl, const float* __restrict__ bl,
    const u16* __restrict__ Xb, int sx,
    u16* __restrict__ Qt, u16* __restrict__ Kt, u16* __restrict__ Vp)
{
    const int mat = blockIdx.z;
    const u16* W = Wl + (size_t)mat * 65536;
    const float* bias = bl + mat * 256;
    const int srcXor = (mat == 0) ? 0 : sx;
    const int tid = threadIdx.x;
    const int wv = tid >> 6, lane = tid & 63, l15 = lane & 15, q = lane >> 4;
    const int r0 = blockIdx.x * 64, o0 = blockIdx.y * 64;
    const int wo = (wv & 1) * 32, wn = (wv >> 1) * 32;
    f32x4 acc[2][2] = {};
    const int oa0 = o0 + wo + l15, oa1 = oa0 + 16;
    const int rb0 = (r0 + wn + l15) ^ srcXor, rb1 = (r0 + wn + 16 + l15) ^ srcXor;
    for (int k0 = 0; k0 < 256; k0 += 32) {
        const int k = k0 + q * 8;
        short8 a0 = ld8(W + (size_t)oa0 * 256 + k);
        short8 a1 = ld8(W + (size_t)oa1 * 256 + k);
        short8 b0 = ld8(Xb + (size_t)rb0 * 256 + k);
        short8 b1 = ld8(Xb + (size_t)rb1 * 256 + k);
        acc[0][0] = __builtin_amdgcn_mfma_f32_16x16x32_bf16(a0, b0, acc[0][0], 0, 0, 0);
        acc[0][1] = __builtin_amdgcn_mfma_f32_16x16x32_bf16(a0, b1, acc[0][1], 0, 0, 0);
        acc[1][0] = __builtin_amdgcn_mfma_f32_16x16x32_bf16(a1, b0, acc[1][0], 0, 0, 0);
        acc[1][1] = __builtin_amdgcn_mfma_f32_16x16x32_bf16(a1, b1, acc[1][1], 0, 0, 0);
    }
    u16* out = (mat == 0) ? Qt : (mat == 1 ? Kt : Vp);
    #pragma unroll
    for (int i = 0; i < 2; i++) {
        const int ob = o0 + wo + i * 16 + q * 4;
        f32x4 bi = *reinterpret_cast<const f32x4*>(bias + ob);
        #pragma unroll
        for (int j = 0; j < 2; j++) {
            const int rr = r0 + wn + j * 16 + l15;
            if (mat < 2) {
                ushort4 pk;
                pk.x = f2b(acc[i][j][0] + bi[0]);
                pk.y = f2b(acc[i][j][1] + bi[1]);
                pk.z = f2b(acc[i][j][2] + bi[2]);
                pk.w = f2b(acc[i][j][3] + bi[3]);
                *reinterpret_cast<ushort4*>(out + (size_t)rr * 256 + ob) = pk;
            } else {
                const int bt = rr >> 10, n = rr & 1023;
                #pragma unroll
                for (int r = 0; r < 4; r++)
                    out[((size_t)bt * 256 + ob + r) * NP + n] = f2b(acc[i][j][r] + bi[r]);
            }
        }
    }
}

// ---------------- split-K flash attention ----------------
__global__ __launch_bounds__(256) void flash_split_kernel(
    const u16* __restrict__ Qt, const u16* __restrict__ Kt, const u16* __restrict__ Vp,
    float* __restrict__ Opart, float2* __restrict__ mlpart)
{
    __shared__ u16 Plds[4][16][72];
    __shared__ float Alds[4][16];
    const int tid = threadIdx.x;
    const int wv = tid >> 6, lane = tid & 63, l15 = lane & 15, q = lane >> 4;
    const int z = blockIdx.y, chunk = blockIdx.z;
    const int bt = z >> 2, h = z & 3;
    const int qrow0 = blockIdx.x * 64 + wv * 16;
    const u16* Qrow = Qt + ((size_t)bt * NP + qrow0) * 256 + 64 * h;
    const u16* Krow = Kt + ((size_t)bt * NP) * 256 + 64 * h;
    const u16* Vrow = Vp + ((size_t)bt * 256 + 64 * h) * NP;

    short8 qf0 = ld8(Qrow + (size_t)l15 * 256 + q * 8);
    short8 qf1 = ld8(Qrow + (size_t)l15 * 256 + 32 + q * 8);

    f32x4 accO[4] = {};
    float mi = -1e30f, li = 0.f;

    const int mEnd = chunk * 256 + 256;
    for (int m0 = chunk * 256; m0 < mEnd; m0 += 64) {
        f32x4 accS[4] = {};
        #pragma unroll
        for (int t = 0; t < 4; t++) {
            const u16* kb = Krow + (size_t)(m0 + 16 * t + l15) * 256 + q * 8;
            short8 kf0 = ld8(kb);
            short8 kf1 = ld8(kb + 32);
            accS[t] = __builtin_amdgcn_mfma_f32_16x16x32_bf16(kf0, qf0, accS[t], 0, 0, 0);
            accS[t] = __builtin_amdgcn_mfma_f32_16x16x32_bf16(kf1, qf1, accS[t], 0, 0, 0);
        }
        float mloc = -1e30f;
        #pragma unroll
        for (int t = 0; t < 4; t++)
            #pragma unroll
            for (int r = 0; r < 4; r++) {
                accS[t][r] *= 0.125f;
                mloc = fmaxf(mloc, accS[t][r]);
            }
        mloc = fmaxf(mloc, __shfl_xor(mloc, 16));
        mloc = fmaxf(mloc, __shfl_xor(mloc, 32));
        float mnew = fmaxf(mi, mloc);
        float alpha = __expf(mi - mnew);
        float psum = 0.f;
        #pragma unroll
        for (int t = 0; t < 4; t++) {
            float e0 = __expf(accS[t][0] - mnew);
            float e1 = __expf(accS[t][1] - mnew);
            float e2 = __expf(accS[t][2] - mnew);
            float e3 = __expf(accS[t][3] - mnew);
            psum += (e0 + e1) + (e2 + e3);
            ushort4 pk;
            pk.x = f2b(e0); pk.y = f2b(e1); pk.z = f2b(e2); pk.w = f2b(e3);
            *reinterpret_cast<ushort4*>(&Plds[wv][l15][16 * t + 4 * q]) = pk;
        }
        psum += __shfl_xor(psum, 16);
        psum += __shfl_xor(psum, 32);
        li = li * alpha + psum;
        mi = mnew;
        if (lane < 16) Alds[wv][l15] = alpha;
        f32x4 av = *reinterpret_cast<f32x4*>(&Alds[wv][4 * q]);
        #pragma unroll
        for (int dt = 0; dt < 4; dt++)
            #pragma unroll
            for (int r = 0; r < 4; r++) accO[dt][r] *= av[r];
        #pragma unroll
        for (int c = 0; c < 2; c++) {
            short8 pf = *reinterpret_cast<short8*>(&Plds[wv][l15][32 * c + q * 8]);
            #pragma unroll
            for (int dt = 0; dt < 4; dt++) {
                short8 vf = ld8(Vrow + (size_t)(16 * dt + l15) * NP + m0 + 32 * c + q * 8);
                accO[dt] = __builtin_amdgcn_mfma_f32_16x16x32_bf16(pf, vf, accO[dt], 0, 0, 0);
            }
        }
    }
    const size_t rowbase = (size_t)(chunk * 16 + z) * NP + qrow0;
    if (lane < 16) mlpart[rowbase + l15] = make_float2(mi, li);
    float* Op = Opart + rowbase * 64;
    #pragma unroll
    for (int dt = 0; dt < 4; dt++)
        #pragma unroll
        for (int r = 0; r < 4; r++)
            Op[(size_t)(4 * q + r) * 64 + 16 * dt + l15] = accO[dt][r];
}

// ---------------- mlp1 (fused merge-weights + fused flash-merge) + BN partial stats ----------------
__global__ __launch_bounds__(256) void mlp1s_mfma(
    const u16* __restrict__ W, const float* __restrict__ bias,
    const u16* __restrict__ Xb, const float* __restrict__ Opart,
    const float2* __restrict__ mlpart,
    u16* __restrict__ outB, float2* __restrict__ part)
{
    __shared__ float bns[64], bnq[64];
    const int tid = threadIdx.x;
    const int wv = tid >> 6, lane = tid & 63, l15 = lane & 15, q = lane >> 4;
    const int r0 = blockIdx.x * 64, o0 = blockIdx.y * 64;
    const int wo = (wv & 1) * 32, wn = (wv >> 1) * 32;
    const int rb0 = r0 + wn + l15, rb1 = rb0 + 16;
    // per-row flash-merge weights: 2 rows x 4 heads x 4 chunks (w_c * invL)
    float wgt[2][4][4];
    #pragma unroll
    for (int rr = 0; rr < 2; rr++) {
        const int rb = rr ? rb1 : rb0;
        const int bt = rb >> 10, n = rb & 1023;
        #pragma unroll
        for (int h = 0; h < 4; h++) {
            const int z = bt * 4 + h;
            float2 ml[4]; float M = -1e30f;
            #pragma unroll
            for (int c = 0; c < 4; c++) {
                ml[c] = mlpart[(size_t)(c * 16 + z) * NP + n];
                M = fmaxf(M, ml[c].x);
            }
            float L = 0.f, w4[4];
            #pragma unroll
            for (int c = 0; c < 4; c++) { w4[c] = __expf(ml[c].x - M); L = fmaf(w4[c], ml[c].y, L); }
            float invL = 1.f / L;
            #pragma unroll
            for (int c = 0; c < 4; c++) wgt[rr][h][c] = w4[c] * invL;
        }
    }
    f32x4 acc[2][2] = {};
    const int oa0 = o0 + wo + l15, oa1 = oa0 + 16;
    for (int k0 = 0; k0 < 512; k0 += 32) {
        const int k = k0 + q * 8;
        short8 a0 = ld8(W + (size_t)oa0 * 512 + k);
        short8 a1 = ld8(W + (size_t)oa1 * 512 + k);
        short8 b0, b1;
        if (k0 < 256) {
            b0 = ld8(Xb + (size_t)rb0 * 256 + k);
            b1 = ld8(Xb + (size_t)rb1 * 256 + k);
        } else {
            const int kk = k - 256;
            const int h = kk >> 6, d0 = kk & 63;
            #pragma unroll
            for (int rr = 0; rr < 2; rr++) {
                const int rb = rr ? rb1 : rb0;
                const int bt = rb >> 10, n = rb & 1023;
                const int z = bt * 4 + h;
                float v[8] = {};
                #pragma unroll
                for (int c = 0; c < 4; c++) {
                    const float* Ob = Opart + (((size_t)(c * 16 + z) * NP + n) * 64 + d0);
                    f32x4 p0 = *reinterpret_cast<const f32x4*>(Ob);
                    f32x4 p1 = *reinterpret_cast<const f32x4*>(Ob + 4);
                    const float wc = wgt[rr][h][c];
                    v[0] = fmaf(wc, p0[0], v[0]); v[1] = fmaf(wc, p0[1], v[1]);
                    v[2] = fmaf(wc, p0[2], v[2]); v[3] = fmaf(wc, p0[3], v[3]);
                    v[4] = fmaf(wc, p1[0], v[4]); v[5] = fmaf(wc, p1[1], v[5]);
                    v[6] = fmaf(wc, p1[2], v[6]); v[7] = fmaf(wc, p1[3], v[7]);
                }
                short8 pk8;
                #pragma unroll
                for (int e = 0; e < 8; e++) pk8[e] = (short)f2b(v[e]);
                if (rr == 0) b0 = pk8; else b1 = pk8;
            }
        }
        acc[0][0] = __builtin_amdgcn_mfma_f32_16x16x32_bf16(a0, b0, acc[0][0], 0, 0, 0);
        acc[0][1] = __builtin_amdgcn_mfma_f32_16x16x32_bf16(a0, b1, acc[0][1], 0, 0, 0);
        acc[1][0] = __builtin_amdgcn_mfma_f32_16x16x32_bf16(a1, b0, acc[1][0], 0, 0, 0);
        acc[1][1] = __builtin_amdgcn_mfma_f32_16x16x32_bf16(a1, b1, acc[1][1], 0, 0, 0);
    }
    if (tid < 64) { bns[tid] = 0.f; bnq[tid] = 0.f; }
    __syncthreads();
    float fv[2][2][4];
    #pragma unroll
    for (int i = 0; i < 2; i++) {
        const int ob = o0 + wo + i * 16 + q * 4;
        f32x4 bi = *reinterpret_cast<const f32x4*>(bias + ob);
        #pragma unroll
        for (int j = 0; j < 2; j++) {
            const int rr = r0 + wn + j * 16 + l15;
            ushort4 pk;
            #pragma unroll
            for (int rg = 0; rg < 4; rg++) fv[i][j][rg] = acc[i][j][rg] + bi[rg];
            pk.x = f2b(fv[i][j][0]); pk.y = f2b(fv[i][j][1]);
            pk.z = f2b(fv[i][j][2]); pk.w = f2b(fv[i][j][3]);
            *reinterpret_cast<ushort4*>(outB + (size_t)rr * 512 + ob) = pk;
        }
    }
    #pragma unroll
    for (int i = 0; i < 2; i++)
        #pragma unroll
        for (int rg = 0; rg < 4; rg++) {
            float s = fv[i][0][rg] + fv[i][1][rg];
            float sq = fv[i][0][rg] * fv[i][0][rg] + fv[i][1][rg] * fv[i][1][rg];
            s += __shfl_xor(s, 1);  sq += __shfl_xor(sq, 1);
            s += __shfl_xor(s, 2);  sq += __shfl_xor(sq, 2);
            s += __shfl_xor(s, 4);  sq += __shfl_xor(sq, 4);
            s += __shfl_xor(s, 8);  sq += __shfl_xor(sq, 8);
            if (l15 == 0) {
                atomicAdd(&bns[wo + i * 16 + q * 4 + rg], s);
                atomicAdd(&bnq[wo + i * 16 + q * 4 + rg], sq);
            }
        }
    __syncthreads();
    if (tid < 64)
        part[(size_t)blockIdx.x * 512 + o0 + tid] = make_float2(bns[tid], bnq[tid]);
}

// ---------------- mlp2 with inline BN finalize + affine + ReLU on B loads ----------------
__device__ __forceinline__ short8 bnrelu8(const u16* __restrict__ p, const float2* sl, int k) {
    short8 raw = ld8(p);
    short8 o;
    #pragma unroll
    for (int e = 0; e < 8; e++) {
        float2 s = sl[k + e];
        float v = fmaf(s.x, b2f((u16)raw[e]), s.y);
        o[e] = (short)f2b(fmaxf(v, 0.f));
    }
    return o;
}

__global__ __launch_bounds__(256) void mlp2_mfma(
    const u16* __restrict__ W, const float* __restrict__ bias,
    const u16* __restrict__ Y, const float2* __restrict__ part,
    const float* __restrict__ g, const float* __restrict__ be,
    float* __restrict__ Xf, u16* __restrict__ Xb)
{
    __shared__ float2 sl[512];
    const int tid = threadIdx.x;
    const int r0 = blockIdx.x * 64, o0 = blockIdx.y * 64;
    const int set = r0 >> 11;
    for (int c = tid; c < 512; c += 256) {
        float sum = 0.f, sq = 0.f;
        #pragma unroll 8
        for (int j = 0; j < 32; j++) {
            float2 p = part[(size_t)(set * 32 + j) * 512 + c];
            sum += p.x; sq += p.y;
        }
        float mu = sum * (1.f / 2048.f);
        float var = fmaxf(sq * (1.f / 2048.f) - mu * mu, 0.f);
        float s1 = g[c] * rsqrtf(var + 1e-5f);
        sl[c] = make_float2(s1, be[c] - s1 * mu);
    }
    __syncthreads();
    const int wv = tid >> 6, lane = tid & 63, l15 = lane & 15, q = lane >> 4;
    const int wo = (wv & 1) * 32, wn = (wv >> 1) * 32;
    f32x4 acc[2][2] = {};
    const int oa0 = o0 + wo + l15, oa1 = oa0 + 16;
    const int rb0 = r0 + wn + l15, rb1 = rb0 + 16;
    for (int k0 = 0; k0 < 512; k0 += 32) {
        const int k = k0 + q * 8;
        short8 a0 = ld8(W + (size_t)oa0 * 512 + k);
        short8 a1 = ld8(W + (size_t)oa1 * 512 + k);
        short8 b0 = bnrelu8(Y + (size_t)rb0 * 512 + k, sl, k);
        short8 b1 = bnrelu8(Y + (size_t)rb1 * 512 + k, sl, k);
        acc[0][0] = __builtin_amdgcn_mfma_f32_16x16x32_bf16(a0, b0, acc[0][0], 0, 0, 0);
        acc[0][1] = __builtin_amdgcn_mfma_f32_16x16x32_bf16(a0, b1, acc[0][1], 0, 0, 0);
        acc[1][0] = __builtin_amdgcn_mfma_f32_16x16x32_bf16(a1, b0, acc[1][0], 0, 0, 0);
        acc[1][1] = __builtin_amdgcn_mfma_f32_16x16x32_bf16(a1, b1, acc[1][1], 0, 0, 0);
    }
    #pragma unroll
    for (int i = 0; i < 2; i++) {
        const int ob = o0 + wo + i * 16 + q * 4;
        f32x4 bi = *reinterpret_cast<const f32x4*>(bias + ob);
        #pragma unroll
        for (int j = 0; j < 2; j++) {
            const int rr = r0 + wn + j * 16 + l15;
            float* xp = Xf + (size_t)rr * 256 + ob;
            f32x4 xo = *reinterpret_cast<f32x4*>(xp);
            #pragma unroll
            for (int r = 0; r < 4; r++) xo[r] += acc[i][j][r] + bi[r];
            *reinterpret_cast<f32x4*>(xp) = xo;
            ushort4 pk;
            pk.x = f2b(xo[0]); pk.y = f2b(xo[1]); pk.z = f2b(xo[2]); pk.w = f2b(xo[3]);
            *reinterpret_cast<ushort4*>(Xb + (size_t)rr * 256 + ob) = pk;
        }
    }
}

// ---------------- final scores MFMA -> Zb and Zt in one dispatch ----------------
__global__ __launch_bounds__(256) void scores_mfma(
    const u16* __restrict__ FT, float* __restrict__ Zb, float* __restrict__ Zt)
{
    const int tid = threadIdx.x;
    const int wv = tid >> 6, lane = tid & 63, l15 = lane & 15, q = lane >> 4;
    const int zz = blockIdx.z;        // 0..3
    const int b = zz & 1, isT = zz >> 1;
    const int m0 = blockIdx.x * 64 + (wv & 1) * 32;
    const int n0 = blockIdx.y * 64 + (wv >> 1) * 32;
    const u16* A  = FT + (size_t)(isT ? 2 + b : b) * NP * 256;
    const u16* Bm = FT + (size_t)(isT ? b : 2 + b) * NP * 256;
    float* outF = (isT ? Zt : Zb) + (size_t)b * ZBS;
    f32x4 acc[2][2] = {};
    const int ma0 = m0 + l15, ma1 = ma0 + 16;
    const int nb0 = n0 + l15, nb1 = nb0 + 16;
    for (int k0 = 0; k0 < 256; k0 += 32) {
        const int k = k0 + q * 8;
        short8 a0 = ld8(A + (size_t)ma0 * 256 + k);
        short8 a1 = ld8(A + (size_t)ma1 * 256 + k);
        short8 b0 = ld8(Bm + (size_t)nb0 * 256 + k);
        short8 b1 = ld8(Bm + (size_t)nb1 * 256 + k);
        acc[0][0] = __builtin_amdgcn_mfma_f32_16x16x32_bf16(a0, b0, acc[0][0], 0, 0, 0);
        acc[0][1] = __builtin_amdgcn_mfma_f32_16x16x32_bf16(a0, b1, acc[0][1], 0, 0, 0);
        acc[1][0] = __builtin_amdgcn_mfma_f32_16x16x32_bf16(a1, b0, acc[1][0], 0, 0, 0);
        acc[1][1] = __builtin_amdgcn_mfma_f32_16x16x32_bf16(a1, b1, acc[1][1], 0, 0, 0);
    }
    #pragma unroll
    for (int i = 0; i < 2; i++)
        #pragma unroll
        for (int j = 0; j < 2; j++)
            #pragma unroll
            for (int r = 0; r < 4; r++)
                outF[(size_t)(m0 + i * 16 + q * 4 + r) * ZLD + n0 + j * 16 + l15]
                    = acc[i][j][r] * 0.0625f;
}

// ---------------- sinkhorn: register-resident persistent kernel ----------------
#define SINK_BLOCKS 129
#define ROOT_IDX 512
#define GO_IDX 576

__global__ void sink_init_kernel(float* __restrict__ u, float* __restrict__ v, unsigned* __restrict__ bar)
{
    int t = blockIdx.x * 256 + threadIdx.x;   // grid 18*256 = 4608
    if (t < 2 * UVS) { u[t] = 0.f; v[t] = 0.f; }
    if (t <= GO_IDX) bar[t] = 0u;
}

__device__ __forceinline__ void srow(const float* z, bool useZ, float alphaV,
                                     const float* __restrict__ vv, float* __restrict__ outp,
                                     int i, int lane)
{
    float s[16];
    #pragma unroll
    for (int kk = 0; kk < 4; kk++)
        #pragma unroll
        for (int e = 0; e < 4; e++) {
            float a = vv[kk * 256 + e * 64 + lane];
            s[kk * 4 + e] = (useZ ? z[kk * 4 + e] : alphaV) + a;
        }
    float edge = alphaV + vv[1024];
    float m = edge;
    #pragma unroll
    for (int k = 0; k < 16; k++) m = fmaxf(m, s[k]);
    m = fmaxf(m, __shfl_xor(m, 1));  m = fmaxf(m, __shfl_xor(m, 2));
    m = fmaxf(m, __shfl_xor(m, 4));  m = fmaxf(m, __shfl_xor(m, 8));
    m = fmaxf(m, __shfl_xor(m, 16)); m = fmaxf(m, __shfl_xor(m, 32));
    float sum = 0.f;
    #pragma unroll
    for (int k = 0; k < 16; k++) sum += __expf(s[k] - m);
    sum += __shfl_xor(sum, 1);  sum += __shfl_xor(sum, 2);
    sum += __shfl_xor(sum, 4);  sum += __shfl_xor(sum, 8);
    sum += __shfl_xor(sum, 16); sum += __shfl_xor(sum, 32);
    sum += __expf(edge - m);
    if (lane == 0) {
        float logw = (i < 1024) ? -LOG2048 : (LOG1024 - LOG2048);
        outp[i] = logw - (m + __logf(sum));
    }
}

// two-level tree barrier: 8 group counters (parallel RMW) -> root counter -> broadcast go flag
__device__ __forceinline__ void gridbar(unsigned* __restrict__ bar, unsigned phase, int tid)
{
    __syncthreads();
    if (tid == 0) {
        __threadfence();
        const unsigned g = blockIdx.x & 7;
        const unsigned sz = (g == 0) ? 17u : 16u;   // 129 blocks: g0 has 17 members
        unsigned old = __hip_atomic_fetch_add(&bar[g * 64], 1u, __ATOMIC_ACQ_REL, __HIP_MEMORY_SCOPE_AGENT);
        if (old + 1 == phase * sz) {
            unsigned r = __hip_atomic_fetch_add(&bar[ROOT_IDX], 1u, __ATOMIC_ACQ_REL, __HIP_MEMORY_SCOPE_AGENT);
            if (r + 1 == phase * 8)
                __hip_atomic_store(&bar[GO_IDX], phase, __ATOMIC_RELEASE, __HIP_MEMORY_SCOPE_AGENT);
        }
        while (__hip_atomic_load(&bar[GO_IDX], __ATOMIC_ACQUIRE, __HIP_MEMORY_SCOPE_AGENT) < phase)
            __builtin_amdgcn_s_sleep(1);
    }
    __syncthreads();
}

__global__ __launch_bounds__(1024) void sinkhorn_kernel(
    const float* __restrict__ Zb, const float* __restrict__ Zt,
    const float* __restrict__ alpha_p, float* __restrict__ uvec, float* __restrict__ vvec,
    unsigned* __restrict__ bar, float* __restrict__ out)
{
    const float alphaV = *alpha_p;
    const int tid = threadIdx.x, wv = tid >> 6, lane = tid & 63;
    const int gw = blockIdx.x * 16 + wv;
    const bool active = gw < 2050;
    const int b = (gw >= 1025) ? 1 : 0;
    const int i = gw - b * 1025;
    const bool useZ = active && (i < 1024);
    float zu[16], zv[16];
    if (useZ) {
        const float* zr = Zb + (size_t)b * ZBS + (size_t)i * ZLD;
        const float* zc = Zt + (size_t)b * ZBS + (size_t)i * ZLD;
        #pragma unroll
        for (int kk = 0; kk < 4; kk++)
            #pragma unroll
            for (int e = 0; e < 4; e++) {
                zu[kk * 4 + e] = zr[kk * 256 + e * 64 + lane];
                zv[kk * 4 + e] = zc[kk * 256 + e * 64 + lane];
            }
    }
    const float* vvb = vvec + b * UVS;
    const float* uub = uvec + b * UVS;
    unsigned phase = 0;
    for (int it = 0; it < 50; it++) {
        if (active) srow(zu, useZ, alphaV, vvb, uvec + b * UVS, i, lane);
        phase++;
        gridbar(bar, phase, tid);
        if (active) srow(zv, useZ, alphaV, uub, vvec + b * UVS, i, lane);
        phase++;
        gridbar(bar, phase, tid);
    }
    if (active) {
        float ui = uub[i];
        float* orow = out + (size_t)b * 1025 * 1025 + (size_t)i * 1025;
        #pragma unroll
        for (int kk = 0; kk < 4; kk++)
            #pragma unroll
            for (int e = 0; e < 4; e++) {
                int m = kk * 256 + e * 64 + lane;
                float zval = useZ ? zu[kk * 4 + e] : alphaV;
                orow[m] = zval + ui + vvb[m] + LOG2048;
            }
        if (lane == 0) orow[1024] = alphaV + ui + vvb[1024] + LOG2048;
    }
}

// =======================================================================
extern "C" void kernel_launch(void* const* d_in, const int* in_sizes, int n_in,
                              void* d_out, int out_size, void* d_ws, size_t ws_size,
                              hipStream_t stream)
{
    (void)in_sizes; (void)n_in; (void)out_size; (void)ws_size;
    const float* kpts0   = (const float*)d_in[0];
    const float* kpts1   = (const float*)d_in[1];
    const float* scores0 = (const float*)d_in[2];
    const float* scores1 = (const float*)d_in[3];
    const float* desc0   = (const float*)d_in[4];
    const float* desc1   = (const float*)d_in[5];
    const float* kenc_w0 = (const float*)d_in[6];
    const float* kenc_b0 = (const float*)d_in[7];
    const float* kenc_g0 = (const float*)d_in[8];
    const float* kenc_be0= (const float*)d_in[9];
    const float* kenc_w1 = (const float*)d_in[10];
    const float* kenc_b1 = (const float*)d_in[11];
    const float* kenc_g1 = (const float*)d_in[12];
    const float* kenc_be1= (const float*)d_in[13];
    const float* kenc_w2 = (const float*)d_in[14];
    const float* kenc_b2 = (const float*)d_in[15];
    const float* kenc_g2 = (const float*)d_in[16];
    const float* kenc_be2= (const float*)d_in[17];
    const float* kenc_w3 = (const float*)d_in[18];
    const float* kenc_b3 = (const float*)d_in[19];
    const float* proj_w  = (const float*)d_in[20];
    const float* proj_b  = (const float*)d_in[21];
    const float* merge_w = (const float*)d_in[22];
    const float* merge_b = (const float*)d_in[23];
    const float* mlp1_w  = (const float*)d_in[24];
    const float* mlp1_b  = (const float*)d_in[25];
    const float* bn_g    = (const float*)d_in[26];
    const float* bn_b    = (const float*)d_in[27];
    const float* mlp2_w  = (const float*)d_in[28];
    const float* mlp2_b  = (const float*)d_in[29];
    const float* final_w = (const float*)d_in[30];
    const float* final_b = (const float*)d_in[31];
    const float* bin_sc  = (const float*)d_in[32];

    char* base = (char*)d_ws;
    size_t off = 0;
    auto alloc = [&](size_t bytes) -> void* {
        void* p = base + off;
        off = (off + bytes + 255) & ~(size_t)255;
        return p;
    };
    float* Zb    = (float*)alloc((size_t)2 * ZBS * 4);
    float* Zt    = (float*)alloc((size_t)2 * ZBS * 4);
    float* X     = (float*)alloc((size_t)4 * NP * 256 * 4);
    u16*  Xb     = (u16*) alloc((size_t)4 * NP * 256 * 2);
    u16*  Qt     = (u16*) alloc((size_t)4 * NP * 256 * 2);
    u16*  Kt     = (u16*) alloc((size_t)4 * NP * 256 * 2);
    u16*  Vp     = (u16*) alloc((size_t)4 * NP * 256 * 2);
    u16*  Y2T    = (u16*) alloc((size_t)4 * NP * 512 * 2);
    u16*  FT     = (u16*) alloc((size_t)4 * NP * 256 * 2);
    float* Opart = (float*)alloc((size_t)4 * 16 * NP * 64 * 4);   // 16.8 MB
    float2* mlp_ = (float2*)alloc((size_t)4 * 16 * NP * 8);
    u16*  Wproj  = (u16*) alloc((size_t)54 * 65536 * 2);
    u16*  WmT    = (u16*) alloc((size_t)18 * 65536 * 2);
    u16*  Wm1f   = (u16*) alloc((size_t)18 * 262144 * 2);
    u16*  Wtmp   = (u16*) alloc((size_t)18 * 131072 * 2);
    u16*  Wmlp2  = (u16*) alloc((size_t)18 * 131072 * 2);
    u16*  Wfin   = (u16*) alloc((size_t)65536 * 2);
    u16*  Wk1    = (u16*) alloc((size_t)64 * 32 * 2);
    u16*  Wk2    = (u16*) alloc((size_t)128 * 64 * 2);
    u16*  Wk3    = (u16*) alloc((size_t)256 * 128 * 2);
    float* pbp   = (float*)alloc((size_t)54 * 256 * 4);
    float* b1p   = (float*)alloc((size_t)18 * 512 * 4);
    float2* part = (float2*)alloc((size_t)64 * 512 * 8);
    float2* s01  = (float2*)alloc((size_t)1024 * 8);
    u16*  A1     = (u16*) alloc((size_t)4096 * 32 * 2);
    u16*  A2     = (u16*) alloc((size_t)4096 * 64 * 2);
    u16*  A3     = (u16*) alloc((size_t)4096 * 128 * 2);
    float* uvec  = (float*)alloc((size_t)2 * UVS * 4);
    float* vvec  = (float*)alloc((size_t)2 * UVS * 4);
    unsigned* bar= (unsigned*)alloc((size_t)(GO_IDX + 64) * 4);

    // -------- weights: cast / permute / fuse --------
    castperm_kernel<<<54 * 65536 / 256, 256, 0, stream>>>(proj_w, Wproj, 256, 256, 1);
    castmergeT_kernel<<<18 * 65536 / 256, 256, 0, stream>>>(merge_w, WmT);
    castsliceA_kernel<<<18 * 512, 256, 0, stream>>>(mlp1_w, Wm1f);
    castsliceB_kernel<<<18 * 512, 256, 0, stream>>>(mlp1_w, Wtmp);
    wfuse_mfma<<<dim3(4, 8, 18), 256, 0, stream>>>(Wtmp, WmT, Wm1f);
    mlp1bias_kernel<<<36, 256, 0, stream>>>(mlp1_w, mlp1_b, merge_b, b1p);
    castperm_kernel<<<18 * 131072 / 256, 256, 0, stream>>>(mlp2_w, Wmlp2, 256, 512, 0);
    castperm_kernel<<<65536 / 256, 256, 0, stream>>>(final_w, Wfin, 256, 256, 0);
    castperm_kernel<<<2048 / 256, 256, 0, stream>>>(kenc_w1, Wk1, 64, 32, 0);
    castperm_kernel<<<8192 / 256, 256, 0, stream>>>(kenc_w2, Wk2, 128, 64, 0);
    castperm_kernel<<<32768 / 256, 256, 0, stream>>>(kenc_w3, Wk3, 256, 128, 0);
    permb_kernel<<<54, 256, 0, stream>>>(proj_b, pbp);
    desc_t_kernel<<<dim3(8, 32, 4), dim3(32, 8), 0, stream>>>(desc0, desc1, X);
    sink_init_kernel<<<18, 256, 0, stream>>>(uvec, vvec, bar);

    // -------- keypoint encoder --------
    kenc1_kernel<<<512, 256, 0, stream>>>(kpts0, kpts1, scores0, scores1, kenc_w0, kenc_b0, A1);
    bn_small_kernel<<<64, 256, 0, stream>>>(A1, 32, kenc_g0, kenc_be0, s01);
    bn_apply_kernel<<<512, 256, 0, stream>>>(A1, s01, 32);
    gemm_mfma<32, 0><<<dim3(64, 1), 256, 0, stream>>>(Wk1, kenc_b1, A1, A1, 32, 0, A2, nullptr, nullptr, 64);
    bn_small_kernel<<<128, 256, 0, stream>>>(A2, 64, kenc_g1, kenc_be1, s01);
    bn_apply_kernel<<<1024, 256, 0, stream>>>(A2, s01, 64);
    gemm_mfma<64, 0><<<dim3(64, 2), 256, 0, stream>>>(Wk2, kenc_b2, A2, A2, 64, 0, A3, nullptr, nullptr, 128);
    bn_small_kernel<<<256, 256, 0, stream>>>(A3, 128, kenc_g2, kenc_be2, s01);
    bn_apply_kernel<<<2048, 256, 0, stream>>>(A3, s01, 128);
    gemm_mfma<128, 2><<<dim3(64, 4), 256, 0, stream>>>(Wk3, kenc_b3, A3, A3, 128, 0, nullptr, X, Xb, 256);

    // -------- 18 GNN layers (4 launches each) --------
    for (int l = 0; l < NL; l++) {
        int sx = (l & 1) ? 2048 : 0;
        qkv_mfma<<<dim3(64, 4, 3), 256, 0, stream>>>(Wproj + (size_t)l * 3 * 65536, pbp + l * 3 * 256,
                                                     Xb, sx, Qt, Kt, Vp);
        flash_split_kernel<<<dim3(16, 16, 4), 256, 0, stream>>>(Qt, Kt, Vp, Opart, mlp_);
        mlp1s_mfma<<<dim3(64, 8), 256, 0, stream>>>(Wm1f + (size_t)l * 262144, b1p + l * 512,
                                                    Xb, Opart, mlp_, Y2T, part);
        mlp2_mfma<<<dim3(64, 4), 256, 0, stream>>>(Wmlp2 + (size_t)l * 131072, mlp2_b + l * 256,
                                                   Y2T, part, bn_g + l * 512, bn_b + l * 512, X, Xb);
    }

    // -------- final projection + scores + optimal transport --------
    gemm_mfma<256, 0><<<dim3(64, 4), 256, 0, stream>>>(Wfin, final_b, Xb, Xb, 256, 0, FT, nullptr, nullptr, 256);
    scores_mfma<<<dim3(16, 16, 4), 256, 0, stream>>>(FT, Zb, Zt);
    sinkhorn_kernel<<<SINK_BLOCKS, 1024, 0, stream>>>(Zb, Zt, bin_sc, uvec, vvec, bar, (float*)d_out);
}

// Round 8
// 2237.072 us; speedup vs baseline: 1.4790x; 1.4790x over previous
//
#include <hip/hip_runtime.h>
#include <hip/hip_bf16.h>
#include <math.h>

#define NP 1024
#define NL 18
#define LOG2048 7.6246189861593985f
#define LOG1024 6.9314718055994531f
#define ZLD 1028           // row stride of Z matrices (floats, 16B-aligned rows)
#define ZBS (1025 * ZLD)   // batch stride
#define UVS 1040           // u/v per-batch stride

typedef __attribute__((ext_vector_type(8))) short short8;
typedef __attribute__((ext_vector_type(4))) float f32x4;
typedef unsigned short u16;

__device__ __forceinline__ u16 f2b(float f) {
    __hip_bfloat16 h = __float2bfloat16(f);
    return *reinterpret_cast<u16*>(&h);
}
__device__ __forceinline__ float b2f(u16 u) {
    __hip_bfloat16 h;
    *reinterpret_cast<u16*>(&h) = u;
    return __bfloat162float(h);
}
__device__ __forceinline__ short8 ld8(const u16* p) { return *reinterpret_cast<const short8*>(p); }

// ---------------- block reduction (blockDim = 256) ----------------
__device__ __forceinline__ float block_reduce_sum(float v, float* red) {
    int tid = threadIdx.x;
    red[tid] = v; __syncthreads();
    for (int s = 128; s > 0; s >>= 1) {
        if (tid < s) red[tid] += red[tid + s];
        __syncthreads();
    }
    float r = red[0]; __syncthreads();
    return r;
}

// ---------------- weight cast / permute ----------------
__global__ void castperm_kernel(const float* __restrict__ src, u16* __restrict__ dst,
                                int R, int C, int mode)
{
    size_t idx = (size_t)blockIdx.x * 256 + threadIdx.x;
    int rc = R * C;
    size_t mat = idx / rc; int rem = (int)(idx % rc);
    int r = rem / C, c = rem % C;
    if (mode == 1) r = ((r & 63) << 2) | (r >> 6);
    dst[idx] = f2b(src[mat * rc + (size_t)r * C + c]);
}

// WmT[l][p][i] = merge_w[l][i][perm(p)]
__global__ void castmergeT_kernel(const float* __restrict__ src, u16* __restrict__ dst)
{
    size_t idx = (size_t)blockIdx.x * 256 + threadIdx.x; // 18*65536
    int l = (int)(idx >> 16);
    int rem = (int)(idx & 65535);
    int p = rem >> 8, i = rem & 255;
    int cp = ((p & 63) << 2) | (p >> 6);
    dst[idx] = f2b(src[(size_t)l * 65536 + (size_t)i * 256 + cp]);
}

__global__ void castsliceA_kernel(const float* __restrict__ src, u16* __restrict__ dst)
{
    size_t idx = (size_t)blockIdx.x * 256 + threadIdx.x; // 18*512*256
    int l = (int)(idx / (512 * 256));
    int rem = (int)(idx % (512 * 256));
    int o = rem >> 8, c = rem & 255;
    dst[(size_t)l * 262144 + (size_t)o * 512 + c] = f2b(src[(size_t)l * 262144 + (size_t)o * 512 + c]);
}

__global__ void castsliceB_kernel(const float* __restrict__ src, u16* __restrict__ dst)
{
    size_t idx = (size_t)blockIdx.x * 256 + threadIdx.x; // 18*512*256
    int l = (int)(idx / (512 * 256));
    int rem = (int)(idx % (512 * 256));
    int o = rem >> 8, i = rem & 255;
    dst[idx] = f2b(src[(size_t)l * 262144 + (size_t)o * 512 + 256 + i]);
}

// Wm1f[l][o][256+p] = sum_i Wtmp[l][o][i] * WmT[l][p][i]
__global__ __launch_bounds__(256) void wfuse_mfma(
    const u16* __restrict__ Wtmp, const u16* __restrict__ WmT, u16* __restrict__ Wm1f)
{
    const int l = blockIdx.z;
    const u16* A = Wtmp + (size_t)l * 131072;
    const u16* B = WmT + (size_t)l * 65536;
    u16* out = Wm1f + (size_t)l * 262144;
    const int tid = threadIdx.x;
    const int wv = tid >> 6, lane = tid & 63, l15 = lane & 15, q = lane >> 4;
    const int r0 = blockIdx.x * 64, o0 = blockIdx.y * 64;
    const int wo = (wv & 1) * 32, wn = (wv >> 1) * 32;
    f32x4 acc[2][2] = {};
    const int oa0 = o0 + wo + l15, oa1 = oa0 + 16;
    const int rb0 = r0 + wn + l15, rb1 = rb0 + 16;
    for (int k0 = 0; k0 < 256; k0 += 32) {
        const int k = k0 + q * 8;
        short8 a0 = ld8(A + (size_t)oa0 * 256 + k);
        short8 a1 = ld8(A + (size_t)oa1 * 256 + k);
        short8 b0 = ld8(B + (size_t)rb0 * 256 + k);
        short8 b1 = ld8(B + (size_t)rb1 * 256 + k);
        acc[0][0] = __builtin_amdgcn_mfma_f32_16x16x32_bf16(a0, b0, acc[0][0], 0, 0, 0);
        acc[0][1] = __builtin_amdgcn_mfma_f32_16x16x32_bf16(a0, b1, acc[0][1], 0, 0, 0);
        acc[1][0] = __builtin_amdgcn_mfma_f32_16x16x32_bf16(a1, b0, acc[1][0], 0, 0, 0);
        acc[1][1] = __builtin_amdgcn_mfma_f32_16x16x32_bf16(a1, b1, acc[1][1], 0, 0, 0);
    }
    #pragma unroll
    for (int i = 0; i < 2; i++)
        #pragma unroll
        for (int j = 0; j < 2; j++)
            #pragma unroll
            for (int rg = 0; rg < 4; rg++)
                out[(size_t)(o0 + wo + i * 16 + q * 4 + rg) * 512 + 256 + r0 + wn + j * 16 + l15]
                    = f2b(acc[i][j][rg]);
}

// b1p[l][o] = mlp1_b[l][o] + sum_i mlp1_w[l][o][256+i]*merge_b[l][i]
__global__ void mlp1bias_kernel(const float* __restrict__ w1, const float* __restrict__ b1,
                                const float* __restrict__ bm, float* __restrict__ b1p)
{
    int idx = blockIdx.x * 256 + threadIdx.x; // 18*512
    int l = idx >> 9, o = idx & 511;
    float s = b1[idx];
    const float* wrow = w1 + (size_t)l * 262144 + (size_t)o * 512 + 256;
    const float* bmr = bm + l * 256;
    for (int i = 0; i < 256; i++) s = fmaf(wrow[i], bmr[i], s);
    b1p[idx] = s;
}

__global__ void permb_kernel(const float* __restrict__ src, float* __restrict__ dst)
{
    int idx = blockIdx.x * 256 + threadIdx.x; // 54*256
    int mat = idx >> 8, r = idx & 255;
    int o = ((r & 63) << 2) | (r >> 6);
    dst[idx] = src[mat * 256 + o];
}

// ---------------- desc -> X (transpose to [bt][n][256] f32) ----------------
__global__ void desc_t_kernel(const float* __restrict__ d0, const float* __restrict__ d1,
                              float* __restrict__ X)
{
    __shared__ float tile[32][33];
    const int bt = blockIdx.z, b = bt & 1;
    const float* d = (bt < 2) ? d0 : d1;
    const int c0 = blockIdx.x * 32, n0 = blockIdx.y * 32;
    for (int rr = threadIdx.y; rr < 32; rr += 8)
        tile[rr][threadIdx.x] = d[((size_t)b * 256 + c0 + rr) * NP + n0 + threadIdx.x];
    __syncthreads();
    for (int rr = threadIdx.y; rr < 32; rr += 8)
        X[((size_t)bt * NP + n0 + rr) * 256 + c0 + threadIdx.x] = tile[threadIdx.x][rr];
}

// ---------------- kenc first conv (3->32) ----------------
__global__ __launch_bounds__(256) void kenc1_kernel(
    const float* __restrict__ k0, const float* __restrict__ k1,
    const float* __restrict__ s0, const float* __restrict__ s1,
    const float* __restrict__ w, const float* __restrict__ bias, u16* __restrict__ A1)
{
    int t = blockIdx.x * 256 + threadIdx.x; // 4096*32
    int r = t >> 5, o = t & 31;
    int bt = r >> 10, n = r & 1023, b = bt & 1;
    const float* kp = (bt < 2) ? k0 : k1;
    const float* sc = (bt < 2) ? s0 : s1;
    float x0 = (kp[((size_t)b * NP + n) * 2 + 0] - 320.f) * (1.f / 448.f);
    float x1 = (kp[((size_t)b * NP + n) * 2 + 1] - 240.f) * (1.f / 448.f);
    float x2 = sc[(size_t)b * NP + n];
    float a = w[o * 3 + 0] * x0 + w[o * 3 + 1] * x1 + w[o * 3 + 2] * x2 + bias[o];
    A1[(size_t)r * 32 + o] = f2b(a);
}

// ---------------- BatchNorm (kenc path) ----------------
__global__ __launch_bounds__(256) void bn_small_kernel(const u16* __restrict__ Xc, int C,
    const float* __restrict__ g, const float* __restrict__ be, float2* __restrict__ s01)
{
    __shared__ float red[256];
    const int s = blockIdx.x / C, c = blockIdx.x % C;
    const int tid = threadIdx.x;
    float sum = 0.f, sq = 0.f;
    const u16* p = Xc + (size_t)s * 2048 * C + c;
    for (int j = tid; j < 2048; j += 256) { float v = b2f(p[(size_t)j * C]); sum += v; sq = fmaf(v, v, sq); }
    sum = block_reduce_sum(sum, red);
    sq  = block_reduce_sum(sq, red);
    if (tid == 0) {
        float mu = sum * (1.f / 2048.f);
        float var = fmaxf(sq * (1.f / 2048.f) - mu * mu, 0.f);
        float s1 = g[c] * rsqrtf(var + 1e-5f);
        s01[s * C + c] = make_float2(s1, be[c] - s1 * mu);
    }
}

__global__ __launch_bounds__(256) void bn_apply_kernel(u16* __restrict__ Xc,
    const float2* __restrict__ s01, int C)
{
    size_t idx = (size_t)blockIdx.x * 256 + threadIdx.x;
    int c = (int)(idx % C);
    int s = (int)(idx / ((size_t)2048 * C));
    float2 p = s01[s * C + c];
    float v = fmaf(p.x, b2f(Xc[idx]), p.y);
    Xc[idx] = f2b(fmaxf(v, 0.f));
}

// ---------------- generic MFMA conv GEMM ----------------
template<int K, int MODE>
__global__ __launch_bounds__(256) void gemm_mfma(
    const u16* __restrict__ W, const float* __restrict__ bias,
    const u16* __restrict__ B1, const u16* __restrict__ B2, int split,
    int srcXor, u16* __restrict__ outB, float* __restrict__ Xf, u16* __restrict__ Xb, int Cout)
{
    const int tid = threadIdx.x;
    const int wv = tid >> 6, lane = tid & 63, l15 = lane & 15, q = lane >> 4;
    const int r0 = blockIdx.x * 64, o0 = blockIdx.y * 64;
    const int wo = (wv & 1) * 32, wn = (wv >> 1) * 32;
    f32x4 acc[2][2] = {};
    const int oa0 = o0 + wo + l15, oa1 = oa0 + 16;
    const int rb0 = (r0 + wn + l15) ^ srcXor, rb1 = (r0 + wn + 16 + l15) ^ srcXor;
    for (int k0 = 0; k0 < K; k0 += 32) {
        const int k = k0 + q * 8;
        short8 a0 = ld8(W + (size_t)oa0 * K + k);
        short8 a1 = ld8(W + (size_t)oa1 * K + k);
        const u16* bp; int ld, kk;
        if (k0 < split) { bp = B1; ld = split; kk = k; }
        else            { bp = B2; ld = K - split; kk = k - split; }
        short8 b0 = ld8(bp + (size_t)rb0 * ld + kk);
        short8 b1 = ld8(bp + (size_t)rb1 * ld + kk);
        acc[0][0] = __builtin_amdgcn_mfma_f32_16x16x32_bf16(a0, b0, acc[0][0], 0, 0, 0);
        acc[0][1] = __builtin_amdgcn_mfma_f32_16x16x32_bf16(a0, b1, acc[0][1], 0, 0, 0);
        acc[1][0] = __builtin_amdgcn_mfma_f32_16x16x32_bf16(a1, b0, acc[1][0], 0, 0, 0);
        acc[1][1] = __builtin_amdgcn_mfma_f32_16x16x32_bf16(a1, b1, acc[1][1], 0, 0, 0);
    }
    #pragma unroll
    for (int i = 0; i < 2; i++) {
        const int ob = o0 + wo + i * 16 + q * 4;
        f32x4 bi = *reinterpret_cast<const f32x4*>(bias + ob);
        #pragma unroll
        for (int j = 0; j < 2; j++) {
            const int rr = r0 + wn + j * 16 + l15;
            if (MODE == 0) {
                ushort4 pk;
                pk.x = f2b(acc[i][j][0] + bi[0]);
                pk.y = f2b(acc[i][j][1] + bi[1]);
                pk.z = f2b(acc[i][j][2] + bi[2]);
                pk.w = f2b(acc[i][j][3] + bi[3]);
                *reinterpret_cast<ushort4*>(outB + (size_t)rr * Cout + ob) = pk;
            } else {
                float* xp = Xf + (size_t)rr * Cout + ob;
                f32x4 xo = *reinterpret_cast<f32x4*>(xp);
                #pragma unroll
                for (int r = 0; r < 4; r++) xo[r] += acc[i][j][r] + bi[r];
                *reinterpret_cast<f32x4*>(xp) = xo;
                ushort4 pk;
                pk.x = f2b(xo[0]); pk.y = f2b(xo[1]); pk.z = f2b(xo[2]); pk.w = f2b(xo[3]);
                *reinterpret_cast<ushort4*>(Xb + (size_t)rr * Cout + ob) = pk;
            }
        }
    }
}

// ---------------- fused QKV projection ----------------
__global__ __launch_bounds__(256) void qkv_mfma(
    const u16* __restrict__ Wl, const float* __restrict__ bl,
    const u16* __restrict__ Xb, int sx,
    u16* __restrict__ Qt, u16* __restrict__ Kt, u16* __restrict__ Vp)
{
    const int mat = blockIdx.z;
    const u16* W = Wl + (size_t)mat * 65536;
    const float* bias = bl + mat * 256;
    const int srcXor = (mat == 0) ? 0 : sx;
    const int tid = threadIdx.x;
    const int wv = tid >> 6, lane = tid & 63, l15 = lane & 15, q = lane >> 4;
    const int r0 = blockIdx.x * 64, o0 = blockIdx.y * 64;
    const int wo = (wv & 1) * 32, wn = (wv >> 1) * 32;
    f32x4 acc[2][2] = {};
    const int oa0 = o0 + wo + l15, oa1 = oa0 + 16;
    const int rb0 = (r0 + wn + l15) ^ srcXor, rb1 = (r0 + wn + 16 + l15) ^ srcXor;
    for (int k0 = 0; k0 < 256; k0 += 32) {
        const int k = k0 + q * 8;
        short8 a0 = ld8(W + (size_t)oa0 * 256 + k);
        short8 a1 = ld8(W + (size_t)oa1 * 256 + k);
        short8 b0 = ld8(Xb + (size_t)rb0 * 256 + k);
        short8 b1 = ld8(Xb + (size_t)rb1 * 256 + k);
        acc[0][0] = __builtin_amdgcn_mfma_f32_16x16x32_bf16(a0, b0, acc[0][0], 0, 0, 0);
        acc[0][1] = __builtin_amdgcn_mfma_f32_16x16x32_bf16(a0, b1, acc[0][1], 0, 0, 0);
        acc[1][0] = __builtin_amdgcn_mfma_f32_16x16x32_bf16(a1, b0, acc[1][0], 0, 0, 0);
        acc[1][1] = __builtin_amdgcn_mfma_f32_16x16x32_bf16(a1, b1, acc[1][1], 0, 0, 0);
    }
    u16* out = (mat == 0) ? Qt : (mat == 1 ? Kt : Vp);
    #pragma unroll
    for (int i = 0; i < 2; i++) {
        const int ob = o0 + wo + i * 16 + q * 4;
        f32x4 bi = *reinterpret_cast<const f32x4*>(bias + ob);
        #pragma unroll
        for (int j = 0; j < 2; j++) {
            const int rr = r0 + wn + j * 16 + l15;
            if (mat < 2) {
                ushort4 pk;
                pk.x = f2b(acc[i][j][0] + bi[0]);
                pk.y = f2b(acc[i][j][1] + bi[1]);
                pk.z = f2b(acc[i][j][2] + bi[2]);
                pk.w = f2b(acc[i][j][3] + bi[3]);
                *reinterpret_cast<ushort4*>(out + (size_t)rr * 256 + ob) = pk;
            } else {
                const int bt = rr >> 10, n = rr & 1023;
                #pragma unroll
                for (int r = 0; r < 4; r++)
                    out[((size_t)bt * 256 + ob + r) * NP + n] = f2b(acc[i][j][r] + bi[r]);
            }
        }
    }
}

// ---------------- split-K flash attention ----------------
__global__ __launch_bounds__(256) void flash_split_kernel(
    const u16* __restrict__ Qt, const u16* __restrict__ Kt, const u16* __restrict__ Vp,
    float* __restrict__ Opart, float2* __restrict__ mlpart)
{
    __shared__ u16 Plds[4][16][72];
    __shared__ float Alds[4][16];
    const int tid = threadIdx.x;
    const int wv = tid >> 6, lane = tid & 63, l15 = lane & 15, q = lane >> 4;
    const int z = blockIdx.y, chunk = blockIdx.z;
    const int bt = z >> 2, h = z & 3;
    const int qrow0 = blockIdx.x * 64 + wv * 16;
    const u16* Qrow = Qt + ((size_t)bt * NP + qrow0) * 256 + 64 * h;
    const u16* Krow = Kt + ((size_t)bt * NP) * 256 + 64 * h;
    const u16* Vrow = Vp + ((size_t)bt * 256 + 64 * h) * NP;

    short8 qf0 = ld8(Qrow + (size_t)l15 * 256 + q * 8);
    short8 qf1 = ld8(Qrow + (size_t)l15 * 256 + 32 + q * 8);

    f32x4 accO[4] = {};
    float mi = -1e30f, li = 0.f;

    const int mEnd = chunk * 256 + 256;
    for (int m0 = chunk * 256; m0 < mEnd; m0 += 64) {
        f32x4 accS[4] = {};
        #pragma unroll
        for (int t = 0; t < 4; t++) {
            const u16* kb = Krow + (size_t)(m0 + 16 * t + l15) * 256 + q * 8;
            short8 kf0 = ld8(kb);
            short8 kf1 = ld8(kb + 32);
            accS[t] = __builtin_amdgcn_mfma_f32_16x16x32_bf16(kf0, qf0, accS[t], 0, 0, 0);
            accS[t] = __builtin_amdgcn_mfma_f32_16x16x32_bf16(kf1, qf1, accS[t], 0, 0, 0);
        }
        float mloc = -1e30f;
        #pragma unroll
        for (int t = 0; t < 4; t++)
            #pragma unroll
            for (int r = 0; r < 4; r++) {
                accS[t][r] *= 0.125f;
                mloc = fmaxf(mloc, accS[t][r]);
            }
        mloc = fmaxf(mloc, __shfl_xor(mloc, 16));
        mloc = fmaxf(mloc, __shfl_xor(mloc, 32));
        float mnew = fmaxf(mi, mloc);
        float alpha = __expf(mi - mnew);
        float psum = 0.f;
        #pragma unroll
        for (int t = 0; t < 4; t++) {
            float e0 = __expf(accS[t][0] - mnew);
            float e1 = __expf(accS[t][1] - mnew);
            float e2 = __expf(accS[t][2] - mnew);
            float e3 = __expf(accS[t][3] - mnew);
            psum += (e0 + e1) + (e2 + e3);
            ushort4 pk;
            pk.x = f2b(e0); pk.y = f2b(e1); pk.z = f2b(e2); pk.w = f2b(e3);
            *reinterpret_cast<ushort4*>(&Plds[wv][l15][16 * t + 4 * q]) = pk;
        }
        psum += __shfl_xor(psum, 16);
        psum += __shfl_xor(psum, 32);
        li = li * alpha + psum;
        mi = mnew;
        if (lane < 16) Alds[wv][l15] = alpha;
        f32x4 av = *reinterpret_cast<f32x4*>(&Alds[wv][4 * q]);
        #pragma unroll
        for (int dt = 0; dt < 4; dt++)
            #pragma unroll
            for (int r = 0; r < 4; r++) accO[dt][r] *= av[r];
        #pragma unroll
        for (int c = 0; c < 2; c++) {
            short8 pf = *reinterpret_cast<short8*>(&Plds[wv][l15][32 * c + q * 8]);
            #pragma unroll
            for (int dt = 0; dt < 4; dt++) {
                short8 vf = ld8(Vrow + (size_t)(16 * dt + l15) * NP + m0 + 32 * c + q * 8);
                accO[dt] = __builtin_amdgcn_mfma_f32_16x16x32_bf16(pf, vf, accO[dt], 0, 0, 0);
            }
        }
    }
    const size_t rowbase = (size_t)(chunk * 16 + z) * NP + qrow0;
    if (lane < 16) mlpart[rowbase + l15] = make_float2(mi, li);
    float* Op = Opart + rowbase * 64;
    #pragma unroll
    for (int dt = 0; dt < 4; dt++)
        #pragma unroll
        for (int r = 0; r < 4; r++)
            Op[(size_t)(4 * q + r) * 64 + 16 * dt + l15] = accO[dt][r];
}

// merge 4 chunks: one wave per (z,row)
__global__ __launch_bounds__(256) void flash_merge_kernel(
    const float* __restrict__ Opart, const float2* __restrict__ mlpart, u16* __restrict__ MSGT)
{
    const int tid = threadIdx.x;
    const int wv = tid >> 6, lane = tid & 63;
    const int gr = blockIdx.x * 4 + wv;  // 0..16383
    const int z = gr >> 10, row = gr & 1023;
    const int bt = z >> 2, h = z & 3;
    float2 ml[4];
    float M = -1e30f;
    #pragma unroll
    for (int c = 0; c < 4; c++) {
        ml[c] = mlpart[(size_t)(c * 16 + z) * NP + row];
        M = fmaxf(M, ml[c].x);
    }
    float L = 0.f, w[4];
    #pragma unroll
    for (int c = 0; c < 4; c++) { w[c] = __expf(ml[c].x - M); L += w[c] * ml[c].y; }
    float invL = 1.f / L;
    float o = 0.f;
    #pragma unroll
    for (int c = 0; c < 4; c++)
        o += w[c] * Opart[((size_t)(c * 16 + z) * NP + row) * 64 + lane];
    MSGT[((size_t)bt * NP + row) * 256 + 64 * h + lane] = f2b(o * invL);
}

// ---------------- mlp1 (fused merge weights) + BN partial stats ----------------
__global__ __launch_bounds__(256) void mlp1s_mfma(
    const u16* __restrict__ W, const float* __restrict__ bias,
    const u16* __restrict__ B1, const u16* __restrict__ B2,
    u16* __restrict__ outB, float2* __restrict__ part)
{
    __shared__ float bns[64], bnq[64];
    const int tid = threadIdx.x;
    const int wv = tid >> 6, lane = tid & 63, l15 = lane & 15, q = lane >> 4;
    const int r0 = blockIdx.x * 64, o0 = blockIdx.y * 64;
    const int wo = (wv & 1) * 32, wn = (wv >> 1) * 32;
    f32x4 acc[2][2] = {};
    const int oa0 = o0 + wo + l15, oa1 = oa0 + 16;
    const int rb0 = r0 + wn + l15, rb1 = rb0 + 16;
    for (int k0 = 0; k0 < 512; k0 += 32) {
        const int k = k0 + q * 8;
        short8 a0 = ld8(W + (size_t)oa0 * 512 + k);
        short8 a1 = ld8(W + (size_t)oa1 * 512 + k);
        const u16* bp; int kk;
        if (k0 < 256) { bp = B1; kk = k; } else { bp = B2; kk = k - 256; }
        short8 b0 = ld8(bp + (size_t)rb0 * 256 + kk);
        short8 b1 = ld8(bp + (size_t)rb1 * 256 + kk);
        acc[0][0] = __builtin_amdgcn_mfma_f32_16x16x32_bf16(a0, b0, acc[0][0], 0, 0, 0);
        acc[0][1] = __builtin_amdgcn_mfma_f32_16x16x32_bf16(a0, b1, acc[0][1], 0, 0, 0);
        acc[1][0] = __builtin_amdgcn_mfma_f32_16x16x32_bf16(a1, b0, acc[1][0], 0, 0, 0);
        acc[1][1] = __builtin_amdgcn_mfma_f32_16x16x32_bf16(a1, b1, acc[1][1], 0, 0, 0);
    }
    if (tid < 64) { bns[tid] = 0.f; bnq[tid] = 0.f; }
    __syncthreads();
    float fv[2][2][4];
    #pragma unroll
    for (int i = 0; i < 2; i++) {
        const int ob = o0 + wo + i * 16 + q * 4;
        f32x4 bi = *reinterpret_cast<const f32x4*>(bias + ob);
        #pragma unroll
        for (int j = 0; j < 2; j++) {
            const int rr = r0 + wn + j * 16 + l15;
            ushort4 pk;
            #pragma unroll
            for (int rg = 0; rg < 4; rg++) fv[i][j][rg] = acc[i][j][rg] + bi[rg];
            pk.x = f2b(fv[i][j][0]); pk.y = f2b(fv[i][j][1]);
            pk.z = f2b(fv[i][j][2]); pk.w = f2b(fv[i][j][3]);
            *reinterpret_cast<ushort4*>(outB + (size_t)rr * 512 + ob) = pk;
        }
    }
    #pragma unroll
    for (int i = 0; i < 2; i++)
        #pragma unroll
        for (int rg = 0; rg < 4; rg++) {
            float s = fv[i][0][rg] + fv[i][1][rg];
            float sq = fv[i][0][rg] * fv[i][0][rg] + fv[i][1][rg] * fv[i][1][rg];
            s += __shfl_xor(s, 1);  sq += __shfl_xor(sq, 1);
            s += __shfl_xor(s, 2);  sq += __shfl_xor(sq, 2);
            s += __shfl_xor(s, 4);  sq += __shfl_xor(sq, 4);
            s += __shfl_xor(s, 8);  sq += __shfl_xor(sq, 8);
            if (l15 == 0) {
                atomicAdd(&bns[wo + i * 16 + q * 4 + rg], s);
                atomicAdd(&bnq[wo + i * 16 + q * 4 + rg], sq);
            }
        }
    __syncthreads();
    if (tid < 64)
        part[(size_t)blockIdx.x * 512 + o0 + tid] = make_float2(bns[tid], bnq[tid]);
}

// ---------------- mlp2 with inline BN finalize + affine + ReLU on B loads ----------------
__device__ __forceinline__ short8 bnrelu8(const u16* __restrict__ p, const float2* sl, int k) {
    short8 raw = ld8(p);
    short8 o;
    #pragma unroll
    for (int e = 0; e < 8; e++) {
        float2 s = sl[k + e];
        float v = fmaf(s.x, b2f((u16)raw[e]), s.y);
        o[e] = (short)f2b(fmaxf(v, 0.f));
    }
    return o;
}

__global__ __launch_bounds__(256) void mlp2_mfma(
    const u16* __restrict__ W, const float* __restrict__ bias,
    const u16* __restrict__ Y, const float2* __restrict__ part,
    const float* __restrict__ g, const float* __restrict__ be,
    float* __restrict__ Xf, u16* __restrict__ Xb)
{
    __shared__ float2 sl[512];
    const int tid = threadIdx.x;
    const int r0 = blockIdx.x * 64, o0 = blockIdx.y * 64;
    const int set = r0 >> 11;
    for (int c = tid; c < 512; c += 256) {
        float sum = 0.f, sq = 0.f;
        #pragma unroll 8
        for (int j = 0; j < 32; j++) {
            float2 p = part[(size_t)(set * 32 + j) * 512 + c];
            sum += p.x; sq += p.y;
        }
        float mu = sum * (1.f / 2048.f);
        float var = fmaxf(sq * (1.f / 2048.f) - mu * mu, 0.f);
        float s1 = g[c] * rsqrtf(var + 1e-5f);
        sl[c] = make_float2(s1, be[c] - s1 * mu);
    }
    __syncthreads();
    const int wv = tid >> 6, lane = tid & 63, l15 = lane & 15, q = lane >> 4;
    const int wo = (wv & 1) * 32, wn = (wv >> 1) * 32;
    f32x4 acc[2][2] = {};
    const int oa0 = o0 + wo + l15, oa1 = oa0 + 16;
    const int rb0 = r0 + wn + l15, rb1 = rb0 + 16;
    for (int k0 = 0; k0 < 512; k0 += 32) {
        const int k = k0 + q * 8;
        short8 a0 = ld8(W + (size_t)oa0 * 512 + k);
        short8 a1 = ld8(W + (size_t)oa1 * 512 + k);
        short8 b0 = bnrelu8(Y + (size_t)rb0 * 512 + k, sl, k);
        short8 b1 = bnrelu8(Y + (size_t)rb1 * 512 + k, sl, k);
        acc[0][0] = __builtin_amdgcn_mfma_f32_16x16x32_bf16(a0, b0, acc[0][0], 0, 0, 0);
        acc[0][1] = __builtin_amdgcn_mfma_f32_16x16x32_bf16(a0, b1, acc[0][1], 0, 0, 0);
        acc[1][0] = __builtin_amdgcn_mfma_f32_16x16x32_bf16(a1, b0, acc[1][0], 0, 0, 0);
        acc[1][1] = __builtin_amdgcn_mfma_f32_16x16x32_bf16(a1, b1, acc[1][1], 0, 0, 0);
    }
    #pragma unroll
    for (int i = 0; i < 2; i++) {
        const int ob = o0 + wo + i * 16 + q * 4;
        f32x4 bi = *reinterpret_cast<const f32x4*>(bias + ob);
        #pragma unroll
        for (int j = 0; j < 2; j++) {
            const int rr = r0 + wn + j * 16 + l15;
            float* xp = Xf + (size_t)rr * 256 + ob;
            f32x4 xo = *reinterpret_cast<f32x4*>(xp);
            #pragma unroll
            for (int r = 0; r < 4; r++) xo[r] += acc[i][j][r] + bi[r];
            *reinterpret_cast<f32x4*>(xp) = xo;
            ushort4 pk;
            pk.x = f2b(xo[0]); pk.y = f2b(xo[1]); pk.z = f2b(xo[2]); pk.w = f2b(xo[3]);
            *reinterpret_cast<ushort4*>(Xb + (size_t)rr * 256 + ob) = pk;
        }
    }
}

// ---------------- final scores MFMA -> Zb and Zt in one dispatch ----------------
__global__ __launch_bounds__(256) void scores_mfma(
    const u16* __restrict__ FT, float* __restrict__ Zb, float* __restrict__ Zt)
{
    const int tid = threadIdx.x;
    const int wv = tid >> 6, lane = tid & 63, l15 = lane & 15, q = lane >> 4;
    const int zz = blockIdx.z;        // 0..3
    const int b = zz & 1, isT = zz >> 1;
    const int m0 = blockIdx.x * 64 + (wv & 1) * 32;
    const int n0 = blockIdx.y * 64 + (wv >> 1) * 32;
    const u16* A  = FT + (size_t)(isT ? 2 + b : b) * NP * 256;
    const u16* Bm = FT + (size_t)(isT ? b : 2 + b) * NP * 256;
    float* outF = (isT ? Zt : Zb) + (size_t)b * ZBS;
    f32x4 acc[2][2] = {};
    const int ma0 = m0 + l15, ma1 = ma0 + 16;
    const int nb0 = n0 + l15, nb1 = nb0 + 16;
    for (int k0 = 0; k0 < 256; k0 += 32) {
        const int k = k0 + q * 8;
        short8 a0 = ld8(A + (size_t)ma0 * 256 + k);
        short8 a1 = ld8(A + (size_t)ma1 * 256 + k);
        short8 b0 = ld8(Bm + (size_t)nb0 * 256 + k);
        short8 b1 = ld8(Bm + (size_t)nb1 * 256 + k);
        acc[0][0] = __builtin_amdgcn_mfma_f32_16x16x32_bf16(a0, b0, acc[0][0], 0, 0, 0);
        acc[0][1] = __builtin_amdgcn_mfma_f32_16x16x32_bf16(a0, b1, acc[0][1], 0, 0, 0);
        acc[1][0] = __builtin_amdgcn_mfma_f32_16x16x32_bf16(a1, b0, acc[1][0], 0, 0, 0);
        acc[1][1] = __builtin_amdgcn_mfma_f32_16x16x32_bf16(a1, b1, acc[1][1], 0, 0, 0);
    }
    #pragma unroll
    for (int i = 0; i < 2; i++)
        #pragma unroll
        for (int j = 0; j < 2; j++)
            #pragma unroll
            for (int r = 0; r < 4; r++)
                outF[(size_t)(m0 + i * 16 + q * 4 + r) * ZLD + n0 + j * 16 + l15]
                    = acc[i][j][r] * 0.0625f;
}

// ---------------- sinkhorn: register-resident persistent kernel ----------------
#define SINK_BLOCKS 129
#define ROOT_IDX 512
#define GO_IDX 576

__global__ void sink_init_kernel(float* __restrict__ u, float* __restrict__ v, unsigned* __restrict__ bar)
{
    int t = blockIdx.x * 256 + threadIdx.x;   // grid 18*256 = 4608
    if (t < 2 * UVS) { u[t] = 0.f; v[t] = 0.f; }
    if (t <= GO_IDX) bar[t] = 0u;
}

__device__ __forceinline__ float aload(const float* p) {
    return __hip_atomic_load(p, __ATOMIC_RELAXED, __HIP_MEMORY_SCOPE_AGENT);
}

// one row LSE update; all cross-block data via device-scope atomics (no fences needed)
__device__ __forceinline__ void srow(const float* z, bool useZ, float alphaV,
                                     const float* __restrict__ vv, float* __restrict__ outp,
                                     int i, int lane)
{
    float s[16];
    #pragma unroll
    for (int kk = 0; kk < 4; kk++)
        #pragma unroll
        for (int e = 0; e < 4; e++) {
            float a = aload(&vv[kk * 256 + e * 64 + lane]);
            s[kk * 4 + e] = (useZ ? z[kk * 4 + e] : alphaV) + a;
        }
    float edge = alphaV + aload(&vv[1024]);
    float m = edge;
    #pragma unroll
    for (int k = 0; k < 16; k++) m = fmaxf(m, s[k]);
    m = fmaxf(m, __shfl_xor(m, 1));  m = fmaxf(m, __shfl_xor(m, 2));
    m = fmaxf(m, __shfl_xor(m, 4));  m = fmaxf(m, __shfl_xor(m, 8));
    m = fmaxf(m, __shfl_xor(m, 16)); m = fmaxf(m, __shfl_xor(m, 32));
    float sum = 0.f;
    #pragma unroll
    for (int k = 0; k < 16; k++) sum += __expf(s[k] - m);
    sum += __shfl_xor(sum, 1);  sum += __shfl_xor(sum, 2);
    sum += __shfl_xor(sum, 4);  sum += __shfl_xor(sum, 8);
    sum += __shfl_xor(sum, 16); sum += __shfl_xor(sum, 32);
    sum += __expf(edge - m);
    if (lane == 0) {
        float logw = (i < 1024) ? -LOG2048 : (LOG1024 - LOG2048);
        __hip_atomic_store(outp + i, logw - (m + __logf(sum)),
                           __ATOMIC_RELAXED, __HIP_MEMORY_SCOPE_AGENT);
    }
}

// fence-free tree barrier: release-RMW arrival (drains the data store via vmcnt wait,
// no cache flush since data stores are device-scope write-through), relaxed broadcast poll
__device__ __forceinline__ void gridbar(unsigned* __restrict__ bar, unsigned phase, int tid)
{
    __syncthreads();
    if (tid == 0) {
        const unsigned g = blockIdx.x & 7;
        const unsigned sz = (g == 0) ? 17u : 16u;   // 129 blocks: group 0 has 17 members
        unsigned old = __hip_atomic_fetch_add(&bar[g * 64], 1u, __ATOMIC_RELEASE, __HIP_MEMORY_SCOPE_AGENT);
        if (old + 1 == phase * sz) {
            unsigned r = __hip_atomic_fetch_add(&bar[ROOT_IDX], 1u, __ATOMIC_RELEASE, __HIP_MEMORY_SCOPE_AGENT);
            if (r + 1 == phase * 8)
                __hip_atomic_store(&bar[GO_IDX], phase, __ATOMIC_RELEASE, __HIP_MEMORY_SCOPE_AGENT);
        }
        while (__hip_atomic_load(&bar[GO_IDX], __ATOMIC_RELAXED, __HIP_MEMORY_SCOPE_AGENT) < phase)
            __builtin_amdgcn_s_sleep(1);
    }
    __syncthreads();
}

__global__ __launch_bounds__(1024) void sinkhorn_kernel(
    const float* __restrict__ Zb, const float* __restrict__ Zt,
    const float* __restrict__ alpha_p, float* __restrict__ uvec, float* __restrict__ vvec,
    unsigned* __restrict__ bar, float* __restrict__ out)
{
    const float alphaV = *alpha_p;
    const int tid = threadIdx.x, wv = tid >> 6, lane = tid & 63;
    const int gw = blockIdx.x * 16 + wv;
    const bool active = gw < 2050;
    const int b = (gw >= 1025) ? 1 : 0;
    const int i = gw - b * 1025;
    const bool useZ = active && (i < 1024);
    float zu[16], zv[16];
    if (useZ) {
        const float* zr = Zb + (size_t)b * ZBS + (size_t)i * ZLD;
        const float* zc = Zt + (size_t)b * ZBS + (size_t)i * ZLD;
        #pragma unroll
        for (int kk = 0; kk < 4; kk++)
            #pragma unroll
            for (int e = 0; e < 4; e++) {
                zu[kk * 4 + e] = zr[kk * 256 + e * 64 + lane];
                zv[kk * 4 + e] = zc[kk * 256 + e * 64 + lane];
            }
    }
    const float* vvb = vvec + b * UVS;
    const float* uub = uvec + b * UVS;
    unsigned phase = 0;
    for (int it = 0; it < 50; it++) {
        if (active) srow(zu, useZ, alphaV, vvb, uvec + b * UVS, i, lane);
        phase++;
        gridbar(bar, phase, tid);
        if (active) srow(zv, useZ, alphaV, uub, vvec + b * UVS, i, lane);
        phase++;
        gridbar(bar, phase, tid);
    }
    if (active) {
        float ui = aload(&uub[i]);
        float* orow = out + (size_t)b * 1025 * 1025 + (size_t)i * 1025;
        #pragma unroll
        for (int kk = 0; kk < 4; kk++)
            #pragma unroll
            for (int e = 0; e < 4; e++) {
                int m = kk * 256 + e * 64 + lane;
                float zval = useZ ? zu[kk * 4 + e] : alphaV;
                orow[m] = zval + ui + aload(&vvb[m]) + LOG2048;
            }
        if (lane == 0) orow[1024] = alphaV + ui + aload(&vvb[1024]) + LOG2048;
    }
}

// =======================================================================
extern "C" void kernel_launch(void* const* d_in, const int* in_sizes, int n_in,
                              void* d_out, int out_size, void* d_ws, size_t ws_size,
                              hipStream_t stream)
{
    (void)in_sizes; (void)n_in; (void)out_size; (void)ws_size;
    const float* kpts0   = (const float*)d_in[0];
    const float* kpts1   = (const float*)d_in[1];
    const float* scores0 = (const float*)d_in[2];
    const float* scores1 = (const float*)d_in[3];
    const float* desc0   = (const float*)d_in[4];
    const float* desc1   = (const float*)d_in[5];
    const float* kenc_w0 = (const float*)d_in[6];
    const float* kenc_b0 = (const float*)d_in[7];
    const float* kenc_g0 = (const float*)d_in[8];
    const float* kenc_be0= (const float*)d_in[9];
    const float* kenc_w1 = (const float*)d_in[10];
    const float* kenc_b1 = (const float*)d_in[11];
    const float* kenc_g1 = (const float*)d_in[12];
    const float* kenc_be1= (const float*)d_in[13];
    const float* kenc_w2 = (const float*)d_in[14];
    const float* kenc_b2 = (const float*)d_in[15];
    const float* kenc_g2 = (const float*)d_in[16];
    const float* kenc_be2= (const float*)d_in[17];
    const float* kenc_w3 = (const float*)d_in[18];
    const float* kenc_b3 = (const float*)d_in[19];
    const float* proj_w  = (const float*)d_in[20];
    const float* proj_b  = (const float*)d_in[21];
    const float* merge_w = (const float*)d_in[22];
    const float* merge_b = (const float*)d_in[23];
    const float* mlp1_w  = (const float*)d_in[24];
    const float* mlp1_b  = (const float*)d_in[25];
    const float* bn_g    = (const float*)d_in[26];
    const float* bn_b    = (const float*)d_in[27];
    const float* mlp2_w  = (const float*)d_in[28];
    const float* mlp2_b  = (const float*)d_in[29];
    const float* final_w = (const float*)d_in[30];
    const float* final_b = (const float*)d_in[31];
    const float* bin_sc  = (const float*)d_in[32];

    char* base = (char*)d_ws;
    size_t off = 0;
    auto alloc = [&](size_t bytes) -> void* {
        void* p = base + off;
        off = (off + bytes + 255) & ~(size_t)255;
        return p;
    };
    float* Zb    = (float*)alloc((size_t)2 * ZBS * 4);
    float* Zt    = (float*)alloc((size_t)2 * ZBS * 4);
    float* X     = (float*)alloc((size_t)4 * NP * 256 * 4);
    u16*  Xb     = (u16*) alloc((size_t)4 * NP * 256 * 2);
    u16*  Qt     = (u16*) alloc((size_t)4 * NP * 256 * 2);
    u16*  Kt     = (u16*) alloc((size_t)4 * NP * 256 * 2);
    u16*  Vp     = (u16*) alloc((size_t)4 * NP * 256 * 2);
    u16*  MSGT   = (u16*) alloc((size_t)4 * NP * 256 * 2);
    u16*  Y2T    = (u16*) alloc((size_t)4 * NP * 512 * 2);
    u16*  FT     = (u16*) alloc((size_t)4 * NP * 256 * 2);
    float* Opart = (float*)alloc((size_t)4 * 16 * NP * 64 * 4);   // 16.8 MB
    float2* mlp_ = (float2*)alloc((size_t)4 * 16 * NP * 8);
    u16*  Wproj  = (u16*) alloc((size_t)54 * 65536 * 2);
    u16*  WmT    = (u16*) alloc((size_t)18 * 65536 * 2);
    u16*  Wm1f   = (u16*) alloc((size_t)18 * 262144 * 2);
    u16*  Wtmp   = (u16*) alloc((size_t)18 * 131072 * 2);
    u16*  Wmlp2  = (u16*) alloc((size_t)18 * 131072 * 2);
    u16*  Wfin   = (u16*) alloc((size_t)65536 * 2);
    u16*  Wk1    = (u16*) alloc((size_t)64 * 32 * 2);
    u16*  Wk2    = (u16*) alloc((size_t)128 * 64 * 2);
    u16*  Wk3    = (u16*) alloc((size_t)256 * 128 * 2);
    float* pbp   = (float*)alloc((size_t)54 * 256 * 4);
    float* b1p   = (float*)alloc((size_t)18 * 512 * 4);
    float2* part = (float2*)alloc((size_t)64 * 512 * 8);
    float2* s01  = (float2*)alloc((size_t)1024 * 8);
    u16*  A1     = (u16*) alloc((size_t)4096 * 32 * 2);
    u16*  A2     = (u16*) alloc((size_t)4096 * 64 * 2);
    u16*  A3     = (u16*) alloc((size_t)4096 * 128 * 2);
    float* uvec  = (float*)alloc((size_t)2 * UVS * 4);
    float* vvec  = (float*)alloc((size_t)2 * UVS * 4);
    unsigned* bar= (unsigned*)alloc((size_t)(GO_IDX + 64) * 4);

    // -------- weights: cast / permute / fuse --------
    castperm_kernel<<<54 * 65536 / 256, 256, 0, stream>>>(proj_w, Wproj, 256, 256, 1);
    castmergeT_kernel<<<18 * 65536 / 256, 256, 0, stream>>>(merge_w, WmT);
    castsliceA_kernel<<<18 * 512, 256, 0, stream>>>(mlp1_w, Wm1f);
    castsliceB_kernel<<<18 * 512, 256, 0, stream>>>(mlp1_w, Wtmp);
    wfuse_mfma<<<dim3(4, 8, 18), 256, 0, stream>>>(Wtmp, WmT, Wm1f);
    mlp1bias_kernel<<<36, 256, 0, stream>>>(mlp1_w, mlp1_b, merge_b, b1p);
    castperm_kernel<<<18 * 131072 / 256, 256, 0, stream>>>(mlp2_w, Wmlp2, 256, 512, 0);
    castperm_kernel<<<65536 / 256, 256, 0, stream>>>(final_w, Wfin, 256, 256, 0);
    castperm_kernel<<<2048 / 256, 256, 0, stream>>>(kenc_w1, Wk1, 64, 32, 0);
    castperm_kernel<<<8192 / 256, 256, 0, stream>>>(kenc_w2, Wk2, 128, 64, 0);
    castperm_kernel<<<32768 / 256, 256, 0, stream>>>(kenc_w3, Wk3, 256, 128, 0);
    permb_kernel<<<54, 256, 0, stream>>>(proj_b, pbp);
    desc_t_kernel<<<dim3(8, 32, 4), dim3(32, 8), 0, stream>>>(desc0, desc1, X);
    sink_init_kernel<<<18, 256, 0, stream>>>(uvec, vvec, bar);

    // -------- keypoint encoder --------
    kenc1_kernel<<<512, 256, 0, stream>>>(kpts0, kpts1, scores0, scores1, kenc_w0, kenc_b0, A1);
    bn_small_kernel<<<64, 256, 0, stream>>>(A1, 32, kenc_g0, kenc_be0, s01);
    bn_apply_kernel<<<512, 256, 0, stream>>>(A1, s01, 32);
    gemm_mfma<32, 0><<<dim3(64, 1), 256, 0, stream>>>(Wk1, kenc_b1, A1, A1, 32, 0, A2, nullptr, nullptr, 64);
    bn_small_kernel<<<128, 256, 0, stream>>>(A2, 64, kenc_g1, kenc_be1, s01);
    bn_apply_kernel<<<1024, 256, 0, stream>>>(A2, s01, 64);
    gemm_mfma<64, 0><<<dim3(64, 2), 256, 0, stream>>>(Wk2, kenc_b2, A2, A2, 64, 0, A3, nullptr, nullptr, 128);
    bn_small_kernel<<<256, 256, 0, stream>>>(A3, 128, kenc_g2, kenc_be2, s01);
    bn_apply_kernel<<<2048, 256, 0, stream>>>(A3, s01, 128);
    gemm_mfma<128, 2><<<dim3(64, 4), 256, 0, stream>>>(Wk3, kenc_b3, A3, A3, 128, 0, nullptr, X, Xb, 256);

    // -------- 18 GNN layers (5 launches each) --------
    for (int l = 0; l < NL; l++) {
        int sx = (l & 1) ? 2048 : 0;
        qkv_mfma<<<dim3(64, 4, 3), 256, 0, stream>>>(Wproj + (size_t)l * 3 * 65536, pbp + l * 3 * 256,
                                                     Xb, sx, Qt, Kt, Vp);
        flash_split_kernel<<<dim3(16, 16, 4), 256, 0, stream>>>(Qt, Kt, Vp, Opart, mlp_);
        flash_merge_kernel<<<4096, 256, 0, stream>>>(Opart, mlp_, MSGT);
        mlp1s_mfma<<<dim3(64, 8), 256, 0, stream>>>(Wm1f + (size_t)l * 262144, b1p + l * 512,
                                                    Xb, MSGT, Y2T, part);
        mlp2_mfma<<<dim3(64, 4), 256, 0, stream>>>(Wmlp2 + (size_t)l * 131072, mlp2_b + l * 256,
                                                   Y2T, part, bn_g + l * 512, bn_b + l * 512, X, Xb);
    }

    // -------- final projection + scores + optimal transport --------
    gemm_mfma<256, 0><<<dim3(64, 4), 256, 0, stream>>>(Wfin, final_b, Xb, Xb, 256, 0, FT, nullptr, nullptr, 256);
    scores_mfma<<<dim3(16, 16, 4), 256, 0, stream>>>(FT, Zb, Zt);
    sinkhorn_kernel<<<SINK_BLOCKS, 1024, 0, stream>>>(Zb, Zt, bin_sc, uvec, vvec, bar, (float*)d_out);
}